// Round 1
// baseline (421.515 us; speedup 1.0000x reference)
//
#include <hip/hip_runtime.h>
#include <math.h>

// ---------------- problem constants ----------------
#define BB 262144
#define NST 20
#define RHc 0.006f            // R*H
#define BHc 0.01f             // B_DRIFT*H
#define SIGc 0.2f
#define CURTc 0.005f
#define DISCf 0.8869204367171575f   // exp(-0.12)

// ---------------- launch geometry ----------------
#define THB_SIM 512
#define NBLK_SIM (BB / THB_SIM)          // 512
#define NBLK_PASS 64
#define EPP (BB / (NBLK_PASS * 256))     // 16 elems/thread
#define NBLK_TAIL 256
#define EPT (BB / (NBLK_TAIL * 256))     // 4 elems/thread

// ---------------- workspace layout (4-byte units) ----------------
#define SIMP_OFF  BB                          // float[NBLK_SIM*5]
#define TAILP_OFF (SIMP_OFF + NBLK_SIM * 5)   // float[NBLK_TAIL*4]
#define ICTRL     (TAILP_OFF + NBLK_TAIL * 4) // int region begins
#define H1_OFF 0
#define H2_OFF 2048
#define H3_OFF (H2_OFF + 4 * 2048)
#define CNT_OFF (H3_OFF + 4 * 1024)           // 8 counters
#define ST_OFF  (CNT_OFF + 8)                 // P1[4] R1[4] G2[4] P2[4] R2[4] G3[4]
#define SF_OFF  (ST_OFF + 24)                 // floats: vals[4], p5, p95
#define CTRL_N  (SF_OFF + 8)                  // ints to zero each call

// ---------------- helpers ----------------
__device__ __forceinline__ unsigned fkey(float f) {
    unsigned u = __float_as_uint(f);
    return (u & 0x80000000u) ? ~u : (u | 0x80000000u);
}
__device__ __forceinline__ float funkey(unsigned k) {
    return __uint_as_float((k & 0x80000000u) ? (k ^ 0x80000000u) : ~k);
}
__device__ __forceinline__ float wred(float v) {
#pragma unroll
    for (int o = 32; o > 0; o >>= 1) v += __shfl_down(v, o);
    return v;
}

// ---------------- zero control region ----------------
__global__ void zero_kernel(int* __restrict__ ctrl) {
    int i = blockIdx.x * blockDim.x + threadIdx.x;
    if (i < CTRL_N) ctrl[i] = 0;
}

// ---------------- main simulation ----------------
__global__ __launch_bounds__(THB_SIM) void sim_kernel(
    const float* __restrict__ x_in, const float* __restrict__ dW,
    const float* __restrict__ Wo, const float* __restrict__ bo,
    const float* __restrict__ Wk, const float* __restrict__ bk,
    const float* __restrict__ Wu0, const float* __restrict__ bu0,
    const float* __restrict__ W1, const float* __restrict__ b1,
    const float* __restrict__ W2, const float* __restrict__ b2,
    const float* __restrict__ W3, const float* __restrict__ b3,
    float* __restrict__ ws, int* __restrict__ ctrl, float* __restrict__ out)
{
    // LDS layout per step s (stride 568 floats, 16B aligned):
    // [0,20) W1row | [20,40) b1 | [40,440) W2 row-major | [440,460) b2 |
    // [460,560) W3T (5 rows x 20) | [560,565) b3 | pad
    __shared__ float L[10844];
    __shared__ float red[8][5];
    __shared__ int lastF;
    const int tid = threadIdx.x;

    for (int t = tid; t < 19 * 20; t += THB_SIM) {
        int s = t / 20, j = t % 20;
        L[s * 568 + j]       = W1[t];
        L[s * 568 + 20 + j]  = b1[t];
        L[s * 568 + 440 + j] = b2[t];
    }
    for (int t = tid; t < 19 * 400; t += THB_SIM) {
        int s = t / 400, r = t % 400;
        L[s * 568 + 40 + r] = W2[t];
    }
    for (int t = tid; t < 19 * 100; t += THB_SIM) {
        int s = t / 100, r = t % 100, i = r / 5, k = r % 5;
        L[s * 568 + 460 + k * 20 + i] = W3[t];
    }
    for (int t = tid; t < 19 * 5; t += THB_SIM) {
        int s = t / 5, k = t % 5;
        L[s * 568 + 560 + k] = b3[t];
    }
    if (tid < 11) { L[10792 + tid] = Wo[tid]; L[10803 + tid] = bo[tid]; }
    if (tid < 10) { L[10814 + tid] = Wk[tid]; L[10824 + tid] = bk[tid]; }
    if (tid < 5)  { L[10834 + tid] = Wu0[tid]; L[10839 + tid] = bu0[tid]; }
    __syncthreads();

    const int b = blockIdx.x * THB_SIM + tid;
    float x = x_in[b];

    // softmax over 11 logits -> last component (loss7 = mean of it)
    float z[11];
    float zmax = -1e30f;
#pragma unroll
    for (int j = 0; j < 11; j++) {
        z[j] = fmaf(x, L[10792 + j], L[10803 + j]);
        zmax = fmaxf(zmax, z[j]);
    }
    float se = 0.f;
#pragma unroll
    for (int j = 0; j < 11; j++) se += __expf(z[j] - zmax);
    float smLast = __expf(z[10] - zmax) / se;

    float K0 = 1.f + 0.25f * tanhf(fmaf(x, L[10814], L[10824]));

    float alpha[5], S[5], SQv[5], dN[5], Nm1[5];
#pragma unroll
    for (int d = 0; d < 5; d++) {
        alpha[d] = fmaf(x, L[10834 + d], L[10839 + d]);
        S[d] = 1.f; SQv[d] = 1.f; dN[d] = 0.f;
        Nm1[d] = alpha[d];   // N_p at n=1 is alpha/1 -> first |diff| = 0
    }

    float dwbuf[5];
#pragma unroll
    for (int d = 0; d < 5; d++) dwbuf[d] = dW[(size_t)b * 5 + d];

#pragma unroll 1
    for (int n = 1; n <= NST; n++) {
        float dwc[5];
#pragma unroll
        for (int d = 0; d < 5; d++) dwc[d] = dwbuf[d];
        if (n < NST) {  // prefetch next step's noise; hides under the MLP
            const float* p = dW + ((size_t)n * BB + b) * 5;
#pragma unroll
            for (int d = 0; d < 5; d++) dwbuf[d] = p[d];
        }
        float usum = 0.f, du = 0.f;
#pragma unroll
        for (int d = 0; d < 5; d++) {
            float u = alpha[d];
            float Np = u * __builtin_amdgcn_rcpf(S[d]);
            dN[d] += fabsf(Np - Nm1[d]);
            Nm1[d] = Np;
            usum += u;
            du = fmaf(u, fmaf(SIGc, dwc[d], BHc), du);
        }
        x = fmaf(x - usum, RHc, x) + du;
#pragma unroll
        for (int d = 0; d < 5; d++) {
            float g = SIGc * dwc[d];
            S[d]   *= (1.f + BHc + g);
            SQv[d] *= (1.f + RHc + g);
        }
        if (n < NST) {
            const float* Ls = L + (n - 1) * 568;
            float h1[20];
#pragma unroll
            for (int j = 0; j < 20; j += 4) {
                float4 w = *(const float4*)(Ls + j);
                float4 c = *(const float4*)(Ls + 20 + j);
                h1[j + 0] = fmaxf(fmaf(x, w.x, c.x), 0.f);
                h1[j + 1] = fmaxf(fmaf(x, w.y, c.y), 0.f);
                h1[j + 2] = fmaxf(fmaf(x, w.z, c.z), 0.f);
                h1[j + 3] = fmaxf(fmaf(x, w.w, c.w), 0.f);
            }
            float h2[20];
#pragma unroll
            for (int j = 0; j < 20; j += 4) {
                float4 c = *(const float4*)(Ls + 440 + j);
                h2[j] = c.x; h2[j + 1] = c.y; h2[j + 2] = c.z; h2[j + 3] = c.w;
            }
#pragma unroll
            for (int i = 0; i < 20; i++) {
                float hi = h1[i];
                const float* wr = Ls + 40 + i * 20;
#pragma unroll
                for (int j = 0; j < 20; j += 4) {
                    float4 w = *(const float4*)(wr + j);
                    h2[j]     = fmaf(hi, w.x, h2[j]);
                    h2[j + 1] = fmaf(hi, w.y, h2[j + 1]);
                    h2[j + 2] = fmaf(hi, w.z, h2[j + 2]);
                    h2[j + 3] = fmaf(hi, w.w, h2[j + 3]);
                }
            }
#pragma unroll
            for (int j = 0; j < 20; j++) h2[j] = fmaxf(h2[j], 0.f);
#pragma unroll
            for (int k = 0; k < 5; k++) {
                float a = Ls[560 + k];
                const float* wr = Ls + 460 + k * 20;
#pragma unroll
                for (int i = 0; i < 20; i += 4) {
                    float4 w = *(const float4*)(wr + i);
                    a = fmaf(h2[i], w.x, a);
                    a = fmaf(h2[i + 1], w.y, a);
                    a = fmaf(h2[i + 2], w.z, a);
                    a = fmaf(h2[i + 3], w.w, a);
                }
                alpha[k] = a;
            }
        }
    }

    float dNs = dN[0] + dN[1] + dN[2] + dN[3] + dN[4];
    x = fmaf(-CURTc, dNs, x);
    ws[b] = x;
    float payP = fmaxf(S[0]   - K0, 0.f);
    float payQ = fmaxf(SQv[0] - K0, 0.f);

    // block partial sums (deterministic tree)
    float v0 = wred(x), v1 = wred(x * x), v2 = wred(payP), v3 = wred(payQ), v4 = wred(smLast);
    int wid = tid >> 6, lane = tid & 63;
    if (lane == 0) { red[wid][0] = v0; red[wid][1] = v1; red[wid][2] = v2; red[wid][3] = v3; red[wid][4] = v4; }
    __syncthreads();
    if (tid == 0) {
        float s0 = 0, s1 = 0, s2 = 0, s3 = 0, s4 = 0;
#pragma unroll
        for (int w = 0; w < 8; w++) { s0 += red[w][0]; s1 += red[w][1]; s2 += red[w][2]; s3 += red[w][3]; s4 += red[w][4]; }
        float* part = ws + SIMP_OFF + blockIdx.x * 5;
        part[0] = s0; part[1] = s1; part[2] = s2; part[3] = s3; part[4] = s4;
    }
    __threadfence();
    if (tid == 0) lastF = (atomicAdd(&ctrl[CNT_OFF + 0], 1) == (int)gridDim.x - 1);
    __syncthreads();
    if (!lastF) return;
    __threadfence();

    // final deterministic reduce of 512 partial rows (one per thread)
    const float* part = ws + SIMP_OFF;
    float a0 = part[tid * 5 + 0], a1 = part[tid * 5 + 1], a2 = part[tid * 5 + 2],
          a3 = part[tid * 5 + 3], a4 = part[tid * 5 + 4];
    a0 = wred(a0); a1 = wred(a1); a2 = wred(a2); a3 = wred(a3); a4 = wred(a4);
    if (lane == 0) { red[wid][0] = a0; red[wid][1] = a1; red[wid][2] = a2; red[wid][3] = a3; red[wid][4] = a4; }
    __syncthreads();
    if (tid == 0) {
        float Sx = 0, Sx2 = 0, SP = 0, SQs = 0, Ssm = 0;
#pragma unroll
        for (int w = 0; w < 8; w++) { Sx += red[w][0]; Sx2 += red[w][1]; SP += red[w][2]; SQs += red[w][3]; Ssm += red[w][4]; }
        float invB = 1.f / (float)BB;
        float meanx = Sx * invB;
        out[0] = -meanx;
        out[1] = Sx2 * invB - meanx * meanx;
        out[4] = (SP * invB) / (DISCf * (SQs * invB) + 1e-8f);
        out[5] = 1.f + 0.25f * tanhf(fmaf(x_in[0], Wk[1], bk[1]));
        out[6] = Ssm * invB;
    }
}

// ---------------- exact radix select (3 passes: 11/11/10 bits) ----------------
template <int PASS>
__global__ __launch_bounds__(256) void pass_kernel(const float* __restrict__ xf,
                                                   int* __restrict__ ctrl)
{
    constexpr int NBIN = (PASS == 3) ? 1024 : 2048;
    constexpr int NG   = (PASS == 1) ? 1 : 4;
    __shared__ int lh[NG * NBIN];
    __shared__ int prefS[4], grpS[4];
    __shared__ int lastF;
    const int tid = threadIdx.x;

    for (int i = tid; i < NG * NBIN; i += 256) lh[i] = 0;
    if (PASS == 2 && tid < 4) { prefS[tid] = ctrl[ST_OFF + 0 + tid];  grpS[tid] = ctrl[ST_OFF + 8 + tid]; }
    if (PASS == 3 && tid < 4) { prefS[tid] = ctrl[ST_OFF + 12 + tid]; grpS[tid] = ctrl[ST_OFF + 20 + tid]; }
    __syncthreads();

    for (int e = 0; e < EPP; e++) {
        int i = blockIdx.x * (256 * EPP) + e * 256 + tid;
        unsigned u = fkey(xf[i]);
        int code;
        if (PASS == 1) {
            code = (int)(u >> 21);
        } else {
            unsigned hi = (PASS == 2) ? (u >> 21) : (u >> 10);
            int bin = (PASS == 2) ? (int)((u >> 10) & 2047u) : (int)(u & 1023u);
            code = -1;
#pragma unroll
            for (int t = 0; t < 4; t++)
                if (grpS[t] == t && (unsigned)prefS[t] == hi) code = t * NBIN + bin;
        }
        // wave-aggregated LDS histogram add (robust to clustered values)
        bool act = (code >= 0);
        unsigned long long mask = __ballot(act);
        while (mask) {
            int leader = __ffsll((unsigned long long)mask) - 1;
            int lc = __shfl(code, leader);
            unsigned long long mm = __ballot(act && code == lc);
            if ((tid & 63) == leader) atomicAdd(&lh[lc], (int)__popcll(mm));
            mask &= ~mm;
        }
    }
    __syncthreads();

    int* gh = ctrl + ((PASS == 1) ? H1_OFF : (PASS == 2) ? H2_OFF : H3_OFF);
    for (int i = tid; i < NG * NBIN; i += 256) {
        int v = lh[i];
        if (v) atomicAdd(&gh[i], v);
    }
    __threadfence();
    if (tid == 0) lastF = (atomicAdd(&ctrl[CNT_OFF + PASS], 1) == (int)gridDim.x - 1);
    __syncthreads();
    if (!lastF) return;
    __threadfence();

    // ------- scan stage (last block only) -------
    __shared__ int csum[256];
    __shared__ int binT[4], remT[4];
    constexpr int PER = NBIN / 256;
    for (int t = 0; t < 4; t++) {
        int g, rank;
        if (PASS == 1) { g = 0; rank = (t == 0) ? 13107 : (t == 1) ? 13108 : (t == 2) ? 249035 : 249036; }
        else if (PASS == 2) { g = ctrl[ST_OFF + 8 + t];  rank = ctrl[ST_OFF + 4 + t]; }
        else                { g = ctrl[ST_OFF + 20 + t]; rank = ctrl[ST_OFF + 16 + t]; }
        const int* h = gh + g * NBIN;
        int s = 0;
#pragma unroll
        for (int j = 0; j < PER; j++) s += h[tid * PER + j];
        csum[tid] = s;
        __syncthreads();
        if (tid == 0) {
            int acc = 0;
            for (int k = 0; k < 256; k++) { int v = csum[k]; csum[k] = acc; acc += v; }
            int cc = 0;
            for (int k = 0; k < 256; k++) { if (csum[k] <= rank) cc = k; else break; }
            int rem = rank - csum[cc];
            int bfound = cc * PER;
            for (int j = 0; j < PER; j++) {
                int v = h[cc * PER + j];
                if (rem < v) { bfound = cc * PER + j; break; }
                rem -= v;
            }
            binT[t] = bfound; remT[t] = rem;
        }
        __syncthreads();
    }
    if (tid == 0) {
        if (PASS == 1) {
            for (int t = 0; t < 4; t++) { ctrl[ST_OFF + t] = binT[t]; ctrl[ST_OFF + 4 + t] = remT[t]; }
            for (int t = 0; t < 4; t++) {
                int g = t;
                for (int q = 0; q < t; q++) if (binT[q] == binT[t]) { g = q; break; }
                ctrl[ST_OFF + 8 + t] = g;
            }
        } else if (PASS == 2) {
            int P2n[4];
            for (int t = 0; t < 4; t++) {
                P2n[t] = (ctrl[ST_OFF + t] << 11) | binT[t];
                ctrl[ST_OFF + 12 + t] = P2n[t];
                ctrl[ST_OFF + 16 + t] = remT[t];
            }
            for (int t = 0; t < 4; t++) {
                int g = t;
                for (int q = 0; q < t; q++) if (P2n[q] == P2n[t]) { g = q; break; }
                ctrl[ST_OFF + 20 + t] = g;
            }
        } else {
            float* sf = (float*)(ctrl + SF_OFF);
            float v[4];
            for (int t = 0; t < 4; t++) {
                unsigned key = ((unsigned)ctrl[ST_OFF + 12 + t] << 10) | (unsigned)binT[t];
                v[t] = funkey(key);
                sf[t] = v[t];
            }
            sf[4] = v[0] + 0.15f * (v[1] - v[0]);  // p5  (idx 0.05*(B-1)=13107.15)
            sf[5] = v[2] + 0.85f * (v[3] - v[2]);  // p95 (idx 0.95*(B-1)=249035.85)
        }
    }
}

// ---------------- tail CVaR sums ----------------
__global__ __launch_bounds__(256) void tail_kernel(const float* __restrict__ ws,
                                                   int* __restrict__ ctrl,
                                                   float* __restrict__ out)
{
    __shared__ float red[4][4];
    __shared__ int lastF;
    const int tid = threadIdx.x;
    const float* sf = (const float*)(ctrl + SF_OFF);
    const float p5 = sf[4], p95 = sf[5];

    float slo = 0.f, shi = 0.f, clo = 0.f, chi = 0.f;
    for (int e = 0; e < EPT; e++) {
        int i = blockIdx.x * (256 * EPT) + e * 256 + tid;
        float x = ws[i];
        if (x < p5)  { slo += x; clo += 1.f; }
        if (x > p95) { shi += x; chi += 1.f; }
    }
    slo = wred(slo); clo = wred(clo); shi = wred(shi); chi = wred(chi);
    int wid = tid >> 6, lane = tid & 63;
    if (lane == 0) { red[wid][0] = slo; red[wid][1] = clo; red[wid][2] = shi; red[wid][3] = chi; }
    __syncthreads();
    if (tid == 0) {
        float s0 = 0, s1 = 0, s2 = 0, s3 = 0;
#pragma unroll
        for (int w = 0; w < 4; w++) { s0 += red[w][0]; s1 += red[w][1]; s2 += red[w][2]; s3 += red[w][3]; }
        float* part = (float*)ws + 0;  // unused; real partials below
        (void)part;
        float* tp = ((float*)ws) + TAILP_OFF + blockIdx.x * 4;
        tp[0] = s0; tp[1] = s1; tp[2] = s2; tp[3] = s3;
    }
    __threadfence();
    if (tid == 0) lastF = (atomicAdd(&ctrl[CNT_OFF + 4], 1) == (int)gridDim.x - 1);
    __syncthreads();
    if (!lastF) return;
    __threadfence();

    const float* tp = ((const float*)ws) + TAILP_OFF;
    float a0 = tp[tid * 4 + 0], a1 = tp[tid * 4 + 1], a2 = tp[tid * 4 + 2], a3 = tp[tid * 4 + 3];
    a0 = wred(a0); a1 = wred(a1); a2 = wred(a2); a3 = wred(a3);
    if (lane == 0) { red[wid][0] = a0; red[wid][1] = a1; red[wid][2] = a2; red[wid][3] = a3; }
    __syncthreads();
    if (tid == 0) {
        float Slo = 0, Clo = 0, Shi = 0, Chi = 0;
#pragma unroll
        for (int w = 0; w < 4; w++) { Slo += red[w][0]; Clo += red[w][1]; Shi += red[w][2]; Chi += red[w][3]; }
        out[2] = -Slo / fmaxf(Clo, 1.f);
        out[3] = -Shi / fmaxf(Chi, 1.f);
    }
}

// ---------------- host ----------------
extern "C" void kernel_launch(void* const* d_in, const int* in_sizes, int n_in,
                              void* d_out, int out_size, void* d_ws, size_t ws_size,
                              hipStream_t stream)
{
    const float* x_in = (const float*)d_in[0];
    const float* dW   = (const float*)d_in[1];
    const float* Wo   = (const float*)d_in[2];
    const float* bo   = (const float*)d_in[3];
    const float* Wk   = (const float*)d_in[4];
    const float* bk   = (const float*)d_in[5];
    const float* Wu0  = (const float*)d_in[6];
    const float* bu0  = (const float*)d_in[7];
    const float* W1   = (const float*)d_in[8];
    const float* b1   = (const float*)d_in[9];
    const float* W2   = (const float*)d_in[10];
    const float* b2   = (const float*)d_in[11];
    const float* W3   = (const float*)d_in[12];
    const float* b3   = (const float*)d_in[13];
    float* ws  = (float*)d_ws;
    int* ctrl  = (int*)d_ws + ICTRL;
    float* out = (float*)d_out;

    zero_kernel<<<(CTRL_N + 255) / 256, 256, 0, stream>>>(ctrl);
    sim_kernel<<<NBLK_SIM, THB_SIM, 0, stream>>>(x_in, dW, Wo, bo, Wk, bk, Wu0, bu0,
                                                 W1, b1, W2, b2, W3, b3, ws, ctrl, out);
    pass_kernel<1><<<NBLK_PASS, 256, 0, stream>>>(ws, ctrl);
    pass_kernel<2><<<NBLK_PASS, 256, 0, stream>>>(ws, ctrl);
    pass_kernel<3><<<NBLK_PASS, 256, 0, stream>>>(ws, ctrl);
    tail_kernel<<<NBLK_TAIL, 256, 0, stream>>>(ws, ctrl, out);
}